// Round 1
// baseline (358.761 us; speedup 1.0000x reference)
//
#include <hip/hip_runtime.h>
#include <cstdint>
#include <cstddef>

static inline int cdiv(int a, int b) { return (a + b - 1) / b; }

// ---------------- setup kernels ----------------

__global__ void zero_kernel(float* __restrict__ p, int n) {
  int i = blockIdx.x * 256 + threadIdx.x;
  if (i < n) p[i] = 0.f;
}

__global__ void diag_kernel(const int* __restrict__ idx, const float* __restrict__ val,
                            float* __restrict__ d, int nnz) {
  int i = blockIdx.x * 256 + threadIdx.x;
  if (i >= nnz) return;
  int r = idx[i], c = idx[nnz + i];
  if (r == c) atomicAdd(&d[r], val[i]);
}

__global__ void dinv_kernel(float* __restrict__ d, int E) {
  int i = blockIdx.x * 256 + threadIdx.x;
  if (i >= E) return;
  float v = d[i];
  d[i] = (v > 0.f) ? 1.0f / sqrtf(fmaxf(v, 1e-12f)) : 0.f;
}

__global__ void count_kernel(const int* __restrict__ idx, int* __restrict__ cnt, int nnz) {
  int i = blockIdx.x * 256 + threadIdx.x;
  if (i >= nnz) return;
  atomicAdd(&cnt[idx[i]], 1);
}

// one block of 1024 threads, n <= 8192 (8 elements/thread), exclusive scan -> rowptr[0..n]
__global__ void scan_kernel(const int* __restrict__ cnt, int* __restrict__ rowptr, int n) {
  __shared__ int part[1024];
  int t = threadIdx.x;
  int base = t * 8;
  int loc[8];
  int s = 0;
#pragma unroll
  for (int k = 0; k < 8; k++) {
    int idx = base + k;
    loc[k] = s;
    s += (idx < n) ? cnt[idx] : 0;
  }
  part[t] = s;
  __syncthreads();
  for (int off = 1; off < 1024; off <<= 1) {
    int v = (t >= off) ? part[t - off] : 0;
    __syncthreads();
    part[t] += v;
    __syncthreads();
  }
  int pre = (t > 0) ? part[t - 1] : 0;
#pragma unroll
  for (int k = 0; k < 8; k++) {
    int idx = base + k;
    if (idx < n) rowptr[idx] = pre + loc[k];
  }
  if (t == 1023) rowptr[n] = part[1023];
}

__global__ void fill_kernel(const int* __restrict__ idx, const float* __restrict__ val,
                            const float* __restrict__ dinv, const int* __restrict__ rowptr,
                            int* __restrict__ cursor, int* __restrict__ colcs,
                            float* __restrict__ valcs, int nnz) {
  int i = blockIdx.x * 256 + threadIdx.x;
  if (i >= nnz) return;
  int r = idx[i], c = idx[nnz + i];
  int p = rowptr[r] + atomicAdd(&cursor[r], 1);
  colcs[p] = c;
  valcs[p] = val[i] * dinv[r] * dinv[c];
}

// ---------------- per-layer kernels ----------------

// y[E][do] = x[E][di] @ W[di][do]; block = 8 rows x 32 lanes
__global__ void gemm_kernel(const float* __restrict__ x, const float* __restrict__ W,
                            float* __restrict__ y, int E, int di, int do_) {
  __shared__ float Ws[64 * 32];
  int t = threadIdx.x;
  for (int k = t; k < di * do_; k += 256) Ws[k] = W[k];
  __syncthreads();
  int f = t & 31, rl = t >> 5;
  int row = blockIdx.x * 8 + rl;
  if (row >= E || f >= do_) return;
  float a = 0.f;
  const float* xr = x + (size_t)row * di;
  for (int k = 0; k < di; k++) a += xr[k] * Ws[k * do_ + f];
  y[(size_t)row * do_ + f] = a;
}

__global__ void attn_s_kernel(const float* __restrict__ h, const float* __restrict__ as,
                              const float* __restrict__ ad, float* __restrict__ ssrc,
                              float* __restrict__ sdst, int E, int do_) {
  int i = blockIdx.x * 256 + threadIdx.x;
  if (i >= E) return;
  float s1 = 0.f, s2 = 0.f;
  for (int f = 0; f < do_; f++) {
    float v = h[(size_t)i * do_ + f];
    s1 += v * as[f];
    s2 += v * ad[f];
  }
  ssrc[i] = s1;
  sdst[i] = s2;
}

// acc[r][:] = sum over (u CSR row r) valn*xwp[c][:] + same over d CSR. wave per row.
__global__ void spmm_kernel(const int* __restrict__ rpu, const int* __restrict__ colu,
                            const float* __restrict__ valu, const int* __restrict__ rpd,
                            const int* __restrict__ cold, const float* __restrict__ vald,
                            const float* __restrict__ xwp, float* __restrict__ acc,
                            int E, int do_) {
  int wid = (blockIdx.x * blockDim.x + threadIdx.x) >> 6;
  int lane = threadIdx.x & 63;
  if (wid >= E) return;
  int f = lane & 31, eo = lane >> 5;
  float a = 0.f;
  int b = rpu[wid], e = rpu[wid + 1];
  for (int j = b + eo; j < e; j += 2) {
    int c = colu[j];
    float v = valu[j];
    if (f < do_) a += v * xwp[(size_t)c * do_ + f];
  }
  b = rpd[wid]; e = rpd[wid + 1];
  for (int j = b + eo; j < e; j += 2) {
    int c = cold[j];
    float v = vald[j];
    if (f < do_) a += v * xwp[(size_t)c * do_ + f];
  }
  a += __shfl_xor(a, 32);
  if (lane < do_) acc[(size_t)wid * do_ + lane] = a;
}

// GAT pass over one CSR; acc[r][:] += sum alpha * h[c][:]. wave per row.
__global__ void gat_kernel(const int* __restrict__ rowptr, const int* __restrict__ col,
                           const float* __restrict__ h, const float* __restrict__ ssrc,
                           const float* __restrict__ sdst, float* __restrict__ acc,
                           int do_, int E) {
  int wid = (blockIdx.x * blockDim.x + threadIdx.x) >> 6;
  int lane = threadIdx.x & 63;
  if (wid >= E) return;
  int beg = rowptr[wid], end = rowptr[wid + 1];
  float ssr = ssrc[wid];
  // phase 1: segment max
  float m = -1e30f;
  for (int j = beg + lane; j < end; j += 64) {
    float e = ssr + sdst[col[j]];
    e = (e > 0.f) ? e : 0.2f * e;
    m = fmaxf(m, e);
  }
#pragma unroll
  for (int off = 32; off; off >>= 1) m = fmaxf(m, __shfl_xor(m, off));
  // phase 2: sum exp
  float s = 0.f;
  for (int j = beg + lane; j < end; j += 64) {
    float e = ssr + sdst[col[j]];
    e = (e > 0.f) ? e : 0.2f * e;
    s += expf(e - m);
  }
#pragma unroll
  for (int off = 32; off; off >>= 1) s += __shfl_xor(s, off);
  float inv = 1.0f / (s + 1e-16f);
  // phase 3: weighted gather; lanes = 2 entries x 32 features
  int f = lane & 31, eo = lane >> 5;
  float a = 0.f;
  for (int j = beg + eo; j < end; j += 2) {
    int c = col[j];
    float e = ssr + sdst[c];
    e = (e > 0.f) ? e : 0.2f * e;
    float al = expf(e - m) * inv;
    if (f < do_) a += al * h[(size_t)c * do_ + f];
  }
  a += __shfl_xor(a, 32);
  if (lane < do_) acc[(size_t)wid * do_ + lane] += a;
}

__global__ void relu_kernel(float* __restrict__ a, int n) {
  int i = blockIdx.x * 256 + threadIdx.x;
  if (i < n) a[i] = fmaxf(a[i], 0.f);
}

// ---------------- pooling + softmax ----------------

__global__ void pool_kernel(const float* __restrict__ x, const int* __restrict__ batch,
                            float* __restrict__ sums, float* __restrict__ cntb,
                            int E, int do_) {
  int i = blockIdx.x * 256 + threadIdx.x;
  if (i >= E) return;
  int b = batch[i];
  for (int f = 0; f < do_; f++) atomicAdd(&sums[b * do_ + f], x[(size_t)i * do_ + f]);
  atomicAdd(&cntb[b], 1.0f);
}

__global__ void softmax_kernel(const float* __restrict__ sums, const float* __restrict__ cntb,
                               float* __restrict__ out, int B, int do_) {
  int b = blockIdx.x * blockDim.x + threadIdx.x;
  if (b >= B) return;
  float c = fmaxf(cntb[b], 1.f);
  float p[16];
  float mx = -1e30f;
  for (int f = 0; f < do_; f++) {
    p[f] = sums[b * do_ + f] / c;
    mx = fmaxf(mx, p[f]);
  }
  float s = 0.f;
  for (int f = 0; f < do_; f++) {
    p[f] = expf(p[f] - mx);
    s += p[f];
  }
  for (int f = 0; f < do_; f++) out[b * do_ + f] = p[f] / s;
}

// ---------------- launch ----------------

extern "C" void kernel_launch(void* const* d_in, const int* in_sizes, int n_in,
                              void* d_out, int out_size, void* d_ws, size_t ws_size,
                              hipStream_t stream) {
  const float* X1 = (const float*)d_in[0];
  const int* idx_u = (const int*)d_in[1];
  const float* val_u = (const float*)d_in[2];
  const int* idx_d = (const int*)d_in[3];
  const float* val_d = (const float*)d_in[4];
  const int* batch1 = (const int*)d_in[5];

  const int E = in_sizes[5];
  const int NNZ = in_sizes[2];
  const int F_IN = in_sizes[0] / E;
  const int OUT = in_sizes[19];
  const int Bn = out_size / OUT;

  // bump allocator over workspace
  char* ws = (char*)d_ws;
  size_t off = 0;
  auto alloc = [&](size_t bytes) -> char* {
    char* p = ws + off;
    off = (off + bytes + 255) & ~(size_t)255;
    return p;
  };

  // zero region (contiguous at start of ws)
  float* d_diag = (float*)alloc((size_t)E * 4);
  int* cnt_u = (int*)alloc((size_t)E * 4);
  int* cnt_d = (int*)alloc((size_t)E * 4);
  int* cur_u = (int*)alloc((size_t)E * 4);
  int* cur_d = (int*)alloc((size_t)E * 4);
  float* sums = (float*)alloc((size_t)Bn * 16 * 4);
  float* cntb = (float*)alloc((size_t)Bn * 4);
  size_t zero_end = off;

  int* rowptr_u = (int*)alloc((size_t)(E + 1) * 4);
  int* rowptr_d = (int*)alloc((size_t)(E + 1) * 4);
  int* col_u = (int*)alloc((size_t)NNZ * 4);
  float* valn_u = (float*)alloc((size_t)NNZ * 4);
  int* col_d = (int*)alloc((size_t)NNZ * 4);
  float* valn_d = (float*)alloc((size_t)NNZ * 4);
  float* h = (float*)alloc((size_t)E * 64 * 4);
  float* xwp = (float*)alloc((size_t)E * 64 * 4);
  float* acc = (float*)alloc((size_t)E * 64 * 4);
  float* ssrc = (float*)alloc((size_t)E * 4);
  float* sdst = (float*)alloc((size_t)E * 4);
  (void)ws_size;

  int zn = (int)(zero_end / 4);
  zero_kernel<<<cdiv(zn, 256), 256, 0, stream>>>((float*)d_ws, zn);

  diag_kernel<<<cdiv(NNZ, 256), 256, 0, stream>>>(idx_u, val_u, d_diag, NNZ);
  diag_kernel<<<cdiv(NNZ, 256), 256, 0, stream>>>(idx_d, val_d, d_diag, NNZ);
  dinv_kernel<<<cdiv(E, 256), 256, 0, stream>>>(d_diag, E);

  count_kernel<<<cdiv(NNZ, 256), 256, 0, stream>>>(idx_u, cnt_u, NNZ);
  count_kernel<<<cdiv(NNZ, 256), 256, 0, stream>>>(idx_d, cnt_d, NNZ);
  scan_kernel<<<1, 1024, 0, stream>>>(cnt_u, rowptr_u, E);
  scan_kernel<<<1, 1024, 0, stream>>>(cnt_d, rowptr_d, E);
  fill_kernel<<<cdiv(NNZ, 256), 256, 0, stream>>>(idx_u, val_u, d_diag, rowptr_u, cur_u,
                                                  col_u, valn_u, NNZ);
  fill_kernel<<<cdiv(NNZ, 256), 256, 0, stream>>>(idx_d, val_d, d_diag, rowptr_d, cur_d,
                                                  col_d, valn_d, NNZ);

  const float* x_in = X1;
  int di = F_IN;
  for (int li = 0; li < 4; li++) {
    const float* Wd = (const float*)d_in[6 + 4 * li + 0];
    const float* as = (const float*)d_in[6 + 4 * li + 1];
    const float* ad = (const float*)d_in[6 + 4 * li + 2];
    const float* Wp = (const float*)d_in[6 + 4 * li + 3];
    int do_ = in_sizes[6 + 4 * li + 1];

    gemm_kernel<<<cdiv(E, 8), 256, 0, stream>>>(x_in, Wd, h, E, di, do_);
    gemm_kernel<<<cdiv(E, 8), 256, 0, stream>>>(x_in, Wp, xwp, E, di, do_);
    attn_s_kernel<<<cdiv(E, 256), 256, 0, stream>>>(h, as, ad, ssrc, sdst, E, do_);
    spmm_kernel<<<cdiv(E, 4), 256, 0, stream>>>(rowptr_u, col_u, valn_u, rowptr_d, col_d,
                                                valn_d, xwp, acc, E, do_);
    gat_kernel<<<cdiv(E, 4), 256, 0, stream>>>(rowptr_u, col_u, h, ssrc, sdst, acc, do_, E);
    gat_kernel<<<cdiv(E, 4), 256, 0, stream>>>(rowptr_d, col_d, h, ssrc, sdst, acc, do_, E);
    relu_kernel<<<cdiv(E * do_, 256), 256, 0, stream>>>(acc, E * do_);

    x_in = acc;
    di = do_;
  }

  pool_kernel<<<cdiv(E, 256), 256, 0, stream>>>(acc, batch1, sums, cntb, E, di);
  softmax_kernel<<<1, 64, 0, stream>>>(sums, cntb, (float*)d_out, Bn, di);
}

// Round 2
// 169.968 us; speedup vs baseline: 2.1107x; 2.1107x over previous
//
#include <hip/hip_runtime.h>
#include <cstdint>
#include <cstddef>

static inline int cdiv(int a, int b) { return (a + b - 1) / b; }

// ---------------- setup kernels ----------------

__global__ void zero_kernel(float* __restrict__ p, int n) {
  int i = blockIdx.x * 256 + threadIdx.x;
  if (i < n) p[i] = 0.f;
}

__global__ void diag_kernel(const int* __restrict__ idx, const float* __restrict__ val,
                            float* __restrict__ d, int nnz) {
  int i = blockIdx.x * 256 + threadIdx.x;
  if (i >= nnz) return;
  int r = idx[i], c = idx[nnz + i];
  if (r == c) atomicAdd(&d[r], val[i]);
}

__global__ void dinv_kernel(float* __restrict__ d, int E) {
  int i = blockIdx.x * 256 + threadIdx.x;
  if (i >= E) return;
  float v = d[i];
  d[i] = (v > 0.f) ? 1.0f / sqrtf(fmaxf(v, 1e-12f)) : 0.f;
}

__global__ void count_kernel(const int* __restrict__ idx, int* __restrict__ cnt, int nnz) {
  int i = blockIdx.x * 256 + threadIdx.x;
  if (i >= nnz) return;
  atomicAdd(&cnt[idx[i]], 1);
}

// one block of 1024 threads, n <= 8192 (8 elements/thread), exclusive scan -> rowptr[0..n]
__global__ void scan_kernel(const int* __restrict__ cnt, int* __restrict__ rowptr, int n) {
  __shared__ int part[1024];
  int t = threadIdx.x;
  int base = t * 8;
  int loc[8];
  int s = 0;
#pragma unroll
  for (int k = 0; k < 8; k++) {
    int idx = base + k;
    loc[k] = s;
    s += (idx < n) ? cnt[idx] : 0;
  }
  part[t] = s;
  __syncthreads();
  for (int off = 1; off < 1024; off <<= 1) {
    int v = (t >= off) ? part[t - off] : 0;
    __syncthreads();
    part[t] += v;
    __syncthreads();
  }
  int pre = (t > 0) ? part[t - 1] : 0;
#pragma unroll
  for (int k = 0; k < 8; k++) {
    int idx = base + k;
    if (idx < n) rowptr[idx] = pre + loc[k];
  }
  if (t == 1023) rowptr[n] = part[1023];
}

__global__ void fill_kernel(const int* __restrict__ idx, const float* __restrict__ val,
                            const float* __restrict__ dinv, const int* __restrict__ rowptr,
                            int* __restrict__ cursor, int* __restrict__ colcs,
                            float* __restrict__ valcs, int nnz) {
  int i = blockIdx.x * 256 + threadIdx.x;
  if (i >= nnz) return;
  int r = idx[i], c = idx[nnz + i];
  int p = rowptr[r] + atomicAdd(&cursor[r], 1);
  colcs[p] = c;
  valcs[p] = val[i] * dinv[r] * dinv[c];
}

// ---------------- per-layer kernels ----------------

// h = x@Wd, xwp = x@Wp, ssrc = h@as, sdst = h@ad. block = 8 rows x 32 lanes.
__global__ void gemm2_kernel(const float* __restrict__ x, const float* __restrict__ Wd,
                             const float* __restrict__ Wp, const float* __restrict__ as,
                             const float* __restrict__ ad, float* __restrict__ h,
                             float* __restrict__ xwp, float* __restrict__ ssrc,
                             float* __restrict__ sdst, int E, int di, int do_) {
  __shared__ float Wds[64 * 32];
  __shared__ float Wps[64 * 32];
  __shared__ float avec[64];
  int t = threadIdx.x;
  for (int k = t; k < di * do_; k += 256) {
    Wds[k] = Wd[k];
    Wps[k] = Wp[k];
  }
  if (t < do_) {
    avec[t] = as[t];
    avec[32 + t] = ad[t];
  }
  __syncthreads();
  int f = t & 31, rl = t >> 5;
  int row = blockIdx.x * 8 + rl;
  if (row >= E) return;
  float ah = 0.f, ap = 0.f;
  const float* xr = x + (size_t)row * di;
  if (f < do_) {
    for (int k = 0; k < di; k++) {
      float xv = xr[k];
      ah += xv * Wds[k * do_ + f];
      ap += xv * Wps[k * do_ + f];
    }
  }
  // attention scalars: reduce ah*as[f] across the 32-lane row group
  float v1 = (f < do_) ? ah * avec[f] : 0.f;
  float v2 = (f < do_) ? ah * avec[32 + f] : 0.f;
#pragma unroll
  for (int off = 16; off; off >>= 1) {
    v1 += __shfl_xor(v1, off);
    v2 += __shfl_xor(v2, off);
  }
  if (f == 0) {
    ssrc[row] = v1;
    sdst[row] = v2;
  }
  if (f < do_) {
    h[(size_t)row * do_ + f] = ah;
    xwp[(size_t)row * do_ + f] = ap;
  }
}

// fused per-row message pass: out[r] = relu( SpMM_L(xwp)[r] + GAT_u(h)[r] + GAT_d(h)[r] )
// wave per row.
__global__ void msg_kernel(const int* __restrict__ rpu, const int* __restrict__ colu,
                           const float* __restrict__ valu, const int* __restrict__ rpd,
                           const int* __restrict__ cold, const float* __restrict__ vald,
                           const float* __restrict__ h, const float* __restrict__ xwp,
                           const float* __restrict__ ssrc, const float* __restrict__ sdst,
                           float* __restrict__ out, int do_, int E) {
  int wid = (blockIdx.x * blockDim.x + threadIdx.x) >> 6;
  int lane = threadIdx.x & 63;
  if (wid >= E) return;
  int bu = rpu[wid], eu = rpu[wid + 1];
  int bd = rpd[wid], ed = rpd[wid + 1];
  float ssr = ssrc[wid];
  // phase 1: segment max for both CSRs
  float mu = -1e30f, md = -1e30f;
  for (int j = bu + lane; j < eu; j += 64) {
    float e = ssr + sdst[colu[j]];
    e = (e > 0.f) ? e : 0.2f * e;
    mu = fmaxf(mu, e);
  }
  for (int j = bd + lane; j < ed; j += 64) {
    float e = ssr + sdst[cold[j]];
    e = (e > 0.f) ? e : 0.2f * e;
    md = fmaxf(md, e);
  }
#pragma unroll
  for (int off = 32; off; off >>= 1) {
    mu = fmaxf(mu, __shfl_xor(mu, off));
    md = fmaxf(md, __shfl_xor(md, off));
  }
  // phase 2: sum of exp
  float su = 0.f, sd = 0.f;
  for (int j = bu + lane; j < eu; j += 64) {
    float e = ssr + sdst[colu[j]];
    e = (e > 0.f) ? e : 0.2f * e;
    su += expf(e - mu);
  }
  for (int j = bd + lane; j < ed; j += 64) {
    float e = ssr + sdst[cold[j]];
    e = (e > 0.f) ? e : 0.2f * e;
    sd += expf(e - md);
  }
#pragma unroll
  for (int off = 32; off; off >>= 1) {
    su += __shfl_xor(su, off);
    sd += __shfl_xor(sd, off);
  }
  float invu = 1.0f / (su + 1e-16f);
  float invd = 1.0f / (sd + 1e-16f);
  // phase 3: weighted gather + SpMM; lanes = 2 entries x 32 features
  int f = lane & 31, eo = lane >> 5;
  float a = 0.f;
  for (int j = bu + eo; j < eu; j += 2) {
    int c = colu[j];
    float v = valu[j];
    float e = ssr + sdst[c];
    e = (e > 0.f) ? e : 0.2f * e;
    float al = expf(e - mu) * invu;
    if (f < do_) a += al * h[(size_t)c * do_ + f] + v * xwp[(size_t)c * do_ + f];
  }
  for (int j = bd + eo; j < ed; j += 2) {
    int c = cold[j];
    float v = vald[j];
    float e = ssr + sdst[c];
    e = (e > 0.f) ? e : 0.2f * e;
    float al = expf(e - md) * invd;
    if (f < do_) a += al * h[(size_t)c * do_ + f] + v * xwp[(size_t)c * do_ + f];
  }
  a += __shfl_xor(a, 32);
  if (lane < do_) out[(size_t)wid * do_ + lane] = fmaxf(a, 0.f);
}

// ---------------- pooling + softmax (atomic-free; batch is sorted) ----------------

__global__ void pool_softmax_kernel(const float* __restrict__ x, const int* __restrict__ batch,
                                    float* __restrict__ out, int E, int do_, int B) {
  int b = blockIdx.x;
  int t = threadIdx.x;
  __shared__ int bounds[2];
  if (t < 2) {
    int target = b + t;
    int lo = 0, hi = E;
    while (lo < hi) {
      int mid = (lo + hi) >> 1;
      if (batch[mid] < target) lo = mid + 1;
      else hi = mid;
    }
    bounds[t] = lo;
  }
  __syncthreads();
  int lo = bounds[0], hi = bounds[1];
  float p[16];
#pragma unroll
  for (int f = 0; f < 16; f++) p[f] = 0.f;
  for (int r = lo + t; r < hi; r += 256) {
#pragma unroll
    for (int f = 0; f < 16; f++)
      if (f < do_) p[f] += x[(size_t)r * do_ + f];
  }
#pragma unroll
  for (int f = 0; f < 16; f++) {
    if (f < 10 || f < do_) {
#pragma unroll
      for (int off = 32; off; off >>= 1) p[f] += __shfl_xor(p[f], off);
    }
  }
  __shared__ float sm[4][16];
  int wv = t >> 6, ln = t & 63;
  if (ln == 0) {
#pragma unroll
    for (int f = 0; f < 16; f++)
      if (f < do_) sm[wv][f] = p[f];
  }
  __syncthreads();
  if (t == 0) {
    float cnt = fmaxf((float)(hi - lo), 1.f);
    float q[16];
    float mx = -1e30f;
    for (int f = 0; f < do_; f++) {
      q[f] = (sm[0][f] + sm[1][f] + sm[2][f] + sm[3][f]) / cnt;
      mx = fmaxf(mx, q[f]);
    }
    float s = 0.f;
    for (int f = 0; f < do_; f++) {
      q[f] = expf(q[f] - mx);
      s += q[f];
    }
    for (int f = 0; f < do_; f++) out[b * do_ + f] = q[f] / s;
  }
}

// ---------------- launch ----------------

extern "C" void kernel_launch(void* const* d_in, const int* in_sizes, int n_in,
                              void* d_out, int out_size, void* d_ws, size_t ws_size,
                              hipStream_t stream) {
  const float* X1 = (const float*)d_in[0];
  const int* idx_u = (const int*)d_in[1];
  const float* val_u = (const float*)d_in[2];
  const int* idx_d = (const int*)d_in[3];
  const float* val_d = (const float*)d_in[4];
  const int* batch1 = (const int*)d_in[5];

  const int E = in_sizes[5];
  const int NNZ = in_sizes[2];
  const int F_IN = in_sizes[0] / E;
  const int OUT = in_sizes[19];
  const int Bn = out_size / OUT;

  // bump allocator over workspace
  char* ws = (char*)d_ws;
  size_t off = 0;
  auto alloc = [&](size_t bytes) -> char* {
    char* p = ws + off;
    off = (off + bytes + 255) & ~(size_t)255;
    return p;
  };

  // zero region (contiguous at start of ws)
  float* d_diag = (float*)alloc((size_t)E * 4);
  int* cnt_u = (int*)alloc((size_t)E * 4);
  int* cnt_d = (int*)alloc((size_t)E * 4);
  int* cur_u = (int*)alloc((size_t)E * 4);
  int* cur_d = (int*)alloc((size_t)E * 4);
  size_t zero_end = off;

  int* rowptr_u = (int*)alloc((size_t)(E + 1) * 4);
  int* rowptr_d = (int*)alloc((size_t)(E + 1) * 4);
  int* col_u = (int*)alloc((size_t)NNZ * 4);
  float* valn_u = (float*)alloc((size_t)NNZ * 4);
  int* col_d = (int*)alloc((size_t)NNZ * 4);
  float* valn_d = (float*)alloc((size_t)NNZ * 4);
  float* h = (float*)alloc((size_t)E * 64 * 4);
  float* xwp = (float*)alloc((size_t)E * 64 * 4);
  float* acc = (float*)alloc((size_t)E * 64 * 4);
  float* ssrc = (float*)alloc((size_t)E * 4);
  float* sdst = (float*)alloc((size_t)E * 4);
  (void)ws_size;

  int zn = (int)(zero_end / 4);
  zero_kernel<<<cdiv(zn, 256), 256, 0, stream>>>((float*)d_ws, zn);

  diag_kernel<<<cdiv(NNZ, 256), 256, 0, stream>>>(idx_u, val_u, d_diag, NNZ);
  diag_kernel<<<cdiv(NNZ, 256), 256, 0, stream>>>(idx_d, val_d, d_diag, NNZ);
  dinv_kernel<<<cdiv(E, 256), 256, 0, stream>>>(d_diag, E);

  count_kernel<<<cdiv(NNZ, 256), 256, 0, stream>>>(idx_u, cnt_u, NNZ);
  count_kernel<<<cdiv(NNZ, 256), 256, 0, stream>>>(idx_d, cnt_d, NNZ);
  scan_kernel<<<1, 1024, 0, stream>>>(cnt_u, rowptr_u, E);
  scan_kernel<<<1, 1024, 0, stream>>>(cnt_d, rowptr_d, E);
  fill_kernel<<<cdiv(NNZ, 256), 256, 0, stream>>>(idx_u, val_u, d_diag, rowptr_u, cur_u,
                                                  col_u, valn_u, NNZ);
  fill_kernel<<<cdiv(NNZ, 256), 256, 0, stream>>>(idx_d, val_d, d_diag, rowptr_d, cur_d,
                                                  col_d, valn_d, NNZ);

  const float* x_in = X1;
  int di = F_IN;
  for (int li = 0; li < 4; li++) {
    const float* Wd = (const float*)d_in[6 + 4 * li + 0];
    const float* as = (const float*)d_in[6 + 4 * li + 1];
    const float* ad = (const float*)d_in[6 + 4 * li + 2];
    const float* Wp = (const float*)d_in[6 + 4 * li + 3];
    int do_ = in_sizes[6 + 4 * li + 1];

    gemm2_kernel<<<cdiv(E, 8), 256, 0, stream>>>(x_in, Wd, Wp, as, ad, h, xwp, ssrc, sdst,
                                                 E, di, do_);
    msg_kernel<<<cdiv(E, 4), 256, 0, stream>>>(rowptr_u, col_u, valn_u, rowptr_d, col_d,
                                               valn_d, h, xwp, ssrc, sdst, acc, do_, E);

    x_in = acc;
    di = do_;
  }

  pool_softmax_kernel<<<Bn, 256, 0, stream>>>(acc, batch1, (float*)d_out, E, di, Bn);
}

// Round 3
// 140.603 us; speedup vs baseline: 2.5516x; 1.2089x over previous
//
#include <hip/hip_runtime.h>
#include <cstdint>
#include <cstddef>

static inline int cdiv(int a, int b) { return (a + b - 1) / b; }

__device__ inline float dinvf(float v) {
  return (v > 0.f) ? 1.0f / sqrtf(fmaxf(v, 1e-12f)) : 0.f;
}

// ---------------- setup kernels ----------------

__global__ void zero_kernel(float* __restrict__ p, int n) {
  int i = blockIdx.x * 256 + threadIdx.x;
  if (i < n) p[i] = 0.f;
}

// fused: row counts for both CSRs + diagonal accumulation (grid covers 2*nnz)
__global__ void diagcount_kernel(const int* __restrict__ idx_u, const float* __restrict__ val_u,
                                 const int* __restrict__ idx_d, const float* __restrict__ val_d,
                                 float* __restrict__ diag, int* __restrict__ cnt_u,
                                 int* __restrict__ cnt_d, int nnz) {
  int i = blockIdx.x * 256 + threadIdx.x;
  if (i < nnz) {
    int r = idx_u[i], c = idx_u[nnz + i];
    atomicAdd(&cnt_u[r], 1);
    if (r == c) atomicAdd(&diag[r], val_u[i]);
  } else if (i < 2 * nnz) {
    int j = i - nnz;
    int r = idx_d[j], c = idx_d[nnz + j];
    atomicAdd(&cnt_d[r], 1);
    if (r == c) atomicAdd(&diag[r], val_d[j]);
  }
}

// two blocks of 1024 threads; block 0 scans cnt_u -> rowptr_u, block 1 cnt_d -> rowptr_d
__global__ void scan2_kernel(const int* __restrict__ cnt_u, int* __restrict__ rowptr_u,
                             const int* __restrict__ cnt_d, int* __restrict__ rowptr_d, int n) {
  const int* cnt = (blockIdx.x == 0) ? cnt_u : cnt_d;
  int* rowptr = (blockIdx.x == 0) ? rowptr_u : rowptr_d;
  __shared__ int part[1024];
  int t = threadIdx.x;
  int base = t * 8;
  int loc[8];
  int s = 0;
#pragma unroll
  for (int k = 0; k < 8; k++) {
    int idx = base + k;
    loc[k] = s;
    s += (idx < n) ? cnt[idx] : 0;
  }
  part[t] = s;
  __syncthreads();
  for (int off = 1; off < 1024; off <<= 1) {
    int v = (t >= off) ? part[t - off] : 0;
    __syncthreads();
    part[t] += v;
    __syncthreads();
  }
  int pre = (t > 0) ? part[t - 1] : 0;
#pragma unroll
  for (int k = 0; k < 8; k++) {
    int idx = base + k;
    if (idx < n) rowptr[idx] = pre + loc[k];
  }
  if (t == 1023) rowptr[n] = part[1023];
}

// fused CSR fill for both matrices; dinv computed inline from diag
__global__ void fill2_kernel(const int* __restrict__ idx_u, const float* __restrict__ val_u,
                             const int* __restrict__ idx_d, const float* __restrict__ val_d,
                             const float* __restrict__ diag, const int* __restrict__ rpu,
                             const int* __restrict__ rpd, int* __restrict__ cur_u,
                             int* __restrict__ cur_d, int* __restrict__ col_u,
                             float* __restrict__ valn_u, int* __restrict__ col_d,
                             float* __restrict__ valn_d, int nnz) {
  int i = blockIdx.x * 256 + threadIdx.x;
  if (i < nnz) {
    int r = idx_u[i], c = idx_u[nnz + i];
    int p = rpu[r] + atomicAdd(&cur_u[r], 1);
    col_u[p] = c;
    valn_u[p] = val_u[i] * dinvf(diag[r]) * dinvf(diag[c]);
  } else if (i < 2 * nnz) {
    int j = i - nnz;
    int r = idx_d[j], c = idx_d[nnz + j];
    int p = rpd[r] + atomicAdd(&cur_d[r], 1);
    col_d[p] = c;
    valn_d[p] = val_d[j] * dinvf(diag[r]) * dinvf(diag[c]);
  }
}

// ---------------- layer kernels ----------------

// layer-1 front: h = x@Wd, xwp = x@Wp, ssrc = h@as, sdst = h@ad. block = 8 rows x 32 lanes.
__global__ void gemm2_kernel(const float* __restrict__ x, const float* __restrict__ Wd,
                             const float* __restrict__ Wp, const float* __restrict__ as,
                             const float* __restrict__ ad, float* __restrict__ h,
                             float* __restrict__ xwp, float* __restrict__ ssrc,
                             float* __restrict__ sdst, int E, int di, int do_) {
  __shared__ float Wds[64 * 32];
  __shared__ float Wps[64 * 32];
  __shared__ float avec[64];
  int t = threadIdx.x;
  for (int k = t; k < di * do_; k += 256) {
    Wds[k] = Wd[k];
    Wps[k] = Wp[k];
  }
  if (t < do_) {
    avec[t] = as[t];
    avec[32 + t] = ad[t];
  }
  __syncthreads();
  int f = t & 31, rl = t >> 5;
  int row = blockIdx.x * 8 + rl;
  if (row >= E) return;
  float ah = 0.f, ap = 0.f;
  const float* xr = x + (size_t)row * di;
  if (f < do_) {
    for (int k = 0; k < di; k++) {
      float xv = xr[k];
      ah += xv * Wds[k * do_ + f];
      ap += xv * Wps[k * do_ + f];
    }
  }
  float v1 = (f < do_) ? ah * avec[f] : 0.f;
  float v2 = (f < do_) ? ah * avec[32 + f] : 0.f;
#pragma unroll
  for (int off = 16; off; off >>= 1) {
    v1 += __shfl_xor(v1, off);
    v2 += __shfl_xor(v2, off);
  }
  if (f == 0) {
    ssrc[row] = v1;
    sdst[row] = v2;
  }
  if (f < do_) {
    h[(size_t)row * do_ + f] = ah;
    xwp[(size_t)row * do_ + f] = ap;
  }
}

// fused: msg-pass of current layer (32 feats) + ReLU + GEMM into next layer (do_next<=32)
// + next layer attention scalars. wave per row; 4 waves/block.
__global__ void msgemm_kernel(const int* __restrict__ rpu, const int* __restrict__ colu,
                              const float* __restrict__ valu, const int* __restrict__ rpd,
                              const int* __restrict__ cold, const float* __restrict__ vald,
                              const float* __restrict__ h, const float* __restrict__ xwp,
                              const float* __restrict__ ssrc, const float* __restrict__ sdst,
                              const float* __restrict__ Wdn, const float* __restrict__ Wpn,
                              const float* __restrict__ asn, const float* __restrict__ adn,
                              float* __restrict__ h_out, float* __restrict__ xwp_out,
                              float* __restrict__ ssrc_out, float* __restrict__ sdst_out,
                              int do_next, int E) {
  __shared__ float Ws[2048];  // [0..1023] Wd padded to stride 32, [1024..2047] Wp
  __shared__ float avec[64];
  int t = threadIdx.x;
  for (int idx = t; idx < 32 * do_next; idx += 256) {
    int k = idx / do_next, f = idx % do_next;
    Ws[k * 32 + f] = Wdn[idx];
    Ws[1024 + k * 32 + f] = Wpn[idx];
  }
  if (t < do_next) {
    avec[t] = asn[t];
    avec[32 + t] = adn[t];
  }
  __syncthreads();
  int wid = blockIdx.x * 4 + (t >> 6);
  int lane = t & 63;
  if (wid >= E) return;

  int bu = rpu[wid], eu = rpu[wid + 1];
  int bd = rpd[wid], ed = rpd[wid + 1];
  float ssr = ssrc[wid];
  // phase 1: segment max
  float mu = -1e30f, md = -1e30f;
  for (int j = bu + lane; j < eu; j += 64) {
    float e = ssr + sdst[colu[j]];
    e = (e > 0.f) ? e : 0.2f * e;
    mu = fmaxf(mu, e);
  }
  for (int j = bd + lane; j < ed; j += 64) {
    float e = ssr + sdst[cold[j]];
    e = (e > 0.f) ? e : 0.2f * e;
    md = fmaxf(md, e);
  }
#pragma unroll
  for (int off = 32; off; off >>= 1) {
    mu = fmaxf(mu, __shfl_xor(mu, off));
    md = fmaxf(md, __shfl_xor(md, off));
  }
  // phase 2: sum exp
  float su = 0.f, sd_ = 0.f;
  for (int j = bu + lane; j < eu; j += 64) {
    float e = ssr + sdst[colu[j]];
    e = (e > 0.f) ? e : 0.2f * e;
    su += expf(e - mu);
  }
  for (int j = bd + lane; j < ed; j += 64) {
    float e = ssr + sdst[cold[j]];
    e = (e > 0.f) ? e : 0.2f * e;
    sd_ += expf(e - md);
  }
#pragma unroll
  for (int off = 32; off; off >>= 1) {
    su += __shfl_xor(su, off);
    sd_ += __shfl_xor(sd_, off);
  }
  float invu = 1.0f / (su + 1e-16f);
  float invd = 1.0f / (sd_ + 1e-16f);
  // phase 3: gather; lanes = 2 entries x 32 features (current layer width fixed at 32)
  int f = lane & 31, eo = lane >> 5;
  float a = 0.f;
  for (int j = bu + eo; j < eu; j += 2) {
    int c = colu[j];
    float v = valu[j];
    float e = ssr + sdst[c];
    e = (e > 0.f) ? e : 0.2f * e;
    float al = expf(e - mu) * invu;
    a += al * h[(size_t)c * 32 + f] + v * xwp[(size_t)c * 32 + f];
  }
  for (int j = bd + eo; j < ed; j += 2) {
    int c = cold[j];
    float v = vald[j];
    float e = ssr + sdst[c];
    e = (e > 0.f) ? e : 0.2f * e;
    float al = expf(e - md) * invd;
    a += al * h[(size_t)c * 32 + f] + v * xwp[(size_t)c * 32 + f];
  }
  a += __shfl_xor(a, 32);         // all 64 lanes now hold feature f = lane&31
  float x = fmaxf(a, 0.f);        // ReLU'd layer output, duplicated in both halves

  // GEMM into next layer: lanes<32 compute h' (Wd), lanes>=32 compute xwp' (Wp)
  const float* W = (lane < 32) ? Ws : (Ws + 1024);
  float acc1 = 0.f;
#pragma unroll
  for (int k = 0; k < 32; k++) {
    float xk = __shfl(x, k);
    acc1 += xk * W[k * 32 + f];
  }
  if (f < do_next) {
    if (lane < 32) h_out[(size_t)wid * do_next + f] = acc1;
    else xwp_out[(size_t)wid * do_next + f] = acc1;
  }
  // next-layer attention scalars from h' (lanes<32 hold it)
  float v1 = (lane < 32 && f < do_next) ? acc1 * avec[f] : 0.f;
  float v2 = (lane < 32 && f < do_next) ? acc1 * avec[32 + f] : 0.f;
#pragma unroll
  for (int off = 32; off; off >>= 1) {
    v1 += __shfl_xor(v1, off);
    v2 += __shfl_xor(v2, off);
  }
  if (lane == 0) {
    ssrc_out[wid] = v1;
    sdst_out[wid] = v2;
  }
}

// final layer message pass (general do_), writes ReLU'd output rows
__global__ void msg_kernel(const int* __restrict__ rpu, const int* __restrict__ colu,
                           const float* __restrict__ valu, const int* __restrict__ rpd,
                           const int* __restrict__ cold, const float* __restrict__ vald,
                           const float* __restrict__ h, const float* __restrict__ xwp,
                           const float* __restrict__ ssrc, const float* __restrict__ sdst,
                           float* __restrict__ out, int do_, int E) {
  int wid = (blockIdx.x * blockDim.x + threadIdx.x) >> 6;
  int lane = threadIdx.x & 63;
  if (wid >= E) return;
  int bu = rpu[wid], eu = rpu[wid + 1];
  int bd = rpd[wid], ed = rpd[wid + 1];
  float ssr = ssrc[wid];
  float mu = -1e30f, md = -1e30f;
  for (int j = bu + lane; j < eu; j += 64) {
    float e = ssr + sdst[colu[j]];
    e = (e > 0.f) ? e : 0.2f * e;
    mu = fmaxf(mu, e);
  }
  for (int j = bd + lane; j < ed; j += 64) {
    float e = ssr + sdst[cold[j]];
    e = (e > 0.f) ? e : 0.2f * e;
    md = fmaxf(md, e);
  }
#pragma unroll
  for (int off = 32; off; off >>= 1) {
    mu = fmaxf(mu, __shfl_xor(mu, off));
    md = fmaxf(md, __shfl_xor(md, off));
  }
  float su = 0.f, sd_ = 0.f;
  for (int j = bu + lane; j < eu; j += 64) {
    float e = ssr + sdst[colu[j]];
    e = (e > 0.f) ? e : 0.2f * e;
    su += expf(e - mu);
  }
  for (int j = bd + lane; j < ed; j += 64) {
    float e = ssr + sdst[cold[j]];
    e = (e > 0.f) ? e : 0.2f * e;
    sd_ += expf(e - md);
  }
#pragma unroll
  for (int off = 32; off; off >>= 1) {
    su += __shfl_xor(su, off);
    sd_ += __shfl_xor(sd_, off);
  }
  float invu = 1.0f / (su + 1e-16f);
  float invd = 1.0f / (sd_ + 1e-16f);
  int f = lane & 31, eo = lane >> 5;
  float a = 0.f;
  for (int j = bu + eo; j < eu; j += 2) {
    int c = colu[j];
    float v = valu[j];
    float e = ssr + sdst[c];
    e = (e > 0.f) ? e : 0.2f * e;
    float al = expf(e - mu) * invu;
    if (f < do_) a += al * h[(size_t)c * do_ + f] + v * xwp[(size_t)c * do_ + f];
  }
  for (int j = bd + eo; j < ed; j += 2) {
    int c = cold[j];
    float v = vald[j];
    float e = ssr + sdst[c];
    e = (e > 0.f) ? e : 0.2f * e;
    float al = expf(e - md) * invd;
    if (f < do_) a += al * h[(size_t)c * do_ + f] + v * xwp[(size_t)c * do_ + f];
  }
  a += __shfl_xor(a, 32);
  if (lane < do_) out[(size_t)wid * do_ + lane] = fmaxf(a, 0.f);
}

// ---------------- pooling + softmax (atomic-free; batch is sorted) ----------------

__global__ void pool_softmax_kernel(const float* __restrict__ x, const int* __restrict__ batch,
                                    float* __restrict__ out, int E, int do_, int B) {
  int b = blockIdx.x;
  int t = threadIdx.x;
  __shared__ int bounds[2];
  if (t < 2) {
    int target = b + t;
    int lo = 0, hi = E;
    while (lo < hi) {
      int mid = (lo + hi) >> 1;
      if (batch[mid] < target) lo = mid + 1;
      else hi = mid;
    }
    bounds[t] = lo;
  }
  __syncthreads();
  int lo = bounds[0], hi = bounds[1];
  float p[16];
#pragma unroll
  for (int f = 0; f < 16; f++) p[f] = 0.f;
  for (int r = lo + t; r < hi; r += 256) {
#pragma unroll
    for (int f = 0; f < 16; f++)
      if (f < do_) p[f] += x[(size_t)r * do_ + f];
  }
#pragma unroll
  for (int f = 0; f < 16; f++) {
    if (f < do_) {
#pragma unroll
      for (int off = 32; off; off >>= 1) p[f] += __shfl_xor(p[f], off);
    }
  }
  __shared__ float sm[4][16];
  int wv = t >> 6, ln = t & 63;
  if (ln == 0) {
#pragma unroll
    for (int f = 0; f < 16; f++)
      if (f < do_) sm[wv][f] = p[f];
  }
  __syncthreads();
  if (t == 0) {
    float cnt = fmaxf((float)(hi - lo), 1.f);
    float q[16];
    float mx = -1e30f;
    for (int f = 0; f < do_; f++) {
      q[f] = (sm[0][f] + sm[1][f] + sm[2][f] + sm[3][f]) / cnt;
      mx = fmaxf(mx, q[f]);
    }
    float s = 0.f;
    for (int f = 0; f < do_; f++) {
      q[f] = expf(q[f] - mx);
      s += q[f];
    }
    for (int f = 0; f < do_; f++) out[b * do_ + f] = q[f] / s;
  }
}

// ---------------- launch ----------------

extern "C" void kernel_launch(void* const* d_in, const int* in_sizes, int n_in,
                              void* d_out, int out_size, void* d_ws, size_t ws_size,
                              hipStream_t stream) {
  const float* X1 = (const float*)d_in[0];
  const int* idx_u = (const int*)d_in[1];
  const float* val_u = (const float*)d_in[2];
  const int* idx_d = (const int*)d_in[3];
  const float* val_d = (const float*)d_in[4];
  const int* batch1 = (const int*)d_in[5];

  const int E = in_sizes[5];
  const int NNZ = in_sizes[2];
  const int F_IN = in_sizes[0] / E;
  const int OUT = in_sizes[19];
  const int Bn = out_size / OUT;

  // bump allocator over workspace
  char* ws = (char*)d_ws;
  size_t off = 0;
  auto alloc = [&](size_t bytes) -> char* {
    char* p = ws + off;
    off = (off + bytes + 255) & ~(size_t)255;
    return p;
  };

  // zero region (contiguous at start of ws)
  float* d_diag = (float*)alloc((size_t)E * 4);
  int* cnt_u = (int*)alloc((size_t)E * 4);
  int* cnt_d = (int*)alloc((size_t)E * 4);
  int* cur_u = (int*)alloc((size_t)E * 4);
  int* cur_d = (int*)alloc((size_t)E * 4);
  size_t zero_end = off;

  int* rowptr_u = (int*)alloc((size_t)(E + 1) * 4);
  int* rowptr_d = (int*)alloc((size_t)(E + 1) * 4);
  int* col_u = (int*)alloc((size_t)NNZ * 4);
  float* valn_u = (float*)alloc((size_t)NNZ * 4);
  int* col_d = (int*)alloc((size_t)NNZ * 4);
  float* valn_d = (float*)alloc((size_t)NNZ * 4);
  float* hA = (float*)alloc((size_t)E * 32 * 4);
  float* xwpA = (float*)alloc((size_t)E * 32 * 4);
  float* hB = (float*)alloc((size_t)E * 32 * 4);
  float* xwpB = (float*)alloc((size_t)E * 32 * 4);
  float* acc = (float*)alloc((size_t)E * 32 * 4);
  float* ssA = (float*)alloc((size_t)E * 4);
  float* sdA = (float*)alloc((size_t)E * 4);
  float* ssB = (float*)alloc((size_t)E * 4);
  float* sdB = (float*)alloc((size_t)E * 4);
  (void)ws_size;

  const float* W1d = (const float*)d_in[6];
  const float* a1s = (const float*)d_in[7];
  const float* a1d = (const float*)d_in[8];
  const float* W1p = (const float*)d_in[9];
  const int H = in_sizes[7];  // 32

  int zn = (int)(zero_end / 4);
  zero_kernel<<<cdiv(zn, 256), 256, 0, stream>>>((float*)d_ws, zn);

  diagcount_kernel<<<cdiv(2 * NNZ, 256), 256, 0, stream>>>(idx_u, val_u, idx_d, val_d,
                                                           d_diag, cnt_u, cnt_d, NNZ);
  scan2_kernel<<<2, 1024, 0, stream>>>(cnt_u, rowptr_u, cnt_d, rowptr_d, E);
  fill2_kernel<<<cdiv(2 * NNZ, 256), 256, 0, stream>>>(idx_u, val_u, idx_d, val_d, d_diag,
                                                       rowptr_u, rowptr_d, cur_u, cur_d,
                                                       col_u, valn_u, col_d, valn_d, NNZ);

  // layer 1 front (di=F_IN, do=H)
  gemm2_kernel<<<cdiv(E, 8), 256, 0, stream>>>(X1, W1d, W1p, a1s, a1d, hA, xwpA, ssA, sdA,
                                               E, F_IN, H);

  // layers 1-3 msg fused with layers 2-4 GEMM front
  float* hin = hA; float* xin = xwpA; float* ssin = ssA; float* sdin = sdA;
  float* hout = hB; float* xout = xwpB; float* ssout = ssB; float* sdout = sdB;
  for (int li = 0; li < 3; li++) {
    const float* Wdn = (const float*)d_in[6 + 4 * (li + 1) + 0];
    const float* asn = (const float*)d_in[6 + 4 * (li + 1) + 1];
    const float* adn = (const float*)d_in[6 + 4 * (li + 1) + 2];
    const float* Wpn = (const float*)d_in[6 + 4 * (li + 1) + 3];
    int do_next = in_sizes[6 + 4 * (li + 1) + 1];
    msgemm_kernel<<<cdiv(E, 4), 256, 0, stream>>>(rowptr_u, col_u, valn_u, rowptr_d, col_d,
                                                  valn_d, hin, xin, ssin, sdin, Wdn, Wpn,
                                                  asn, adn, hout, xout, ssout, sdout,
                                                  do_next, E);
    float* tp;
    tp = hin; hin = hout; hout = tp;
    tp = xin; xin = xout; xout = tp;
    tp = ssin; ssin = ssout; ssout = tp;
    tp = sdin; sdin = sdout; sdout = tp;
  }

  // layer 4 msg (do=OUT)
  msg_kernel<<<cdiv(E, 4), 256, 0, stream>>>(rowptr_u, col_u, valn_u, rowptr_d, col_d,
                                             valn_d, hin, xin, ssin, sdin, acc, OUT, E);

  pool_softmax_kernel<<<Bn, 256, 0, stream>>>(acc, batch1, (float*)d_out, E, OUT, Bn);
}

// Round 4
// 125.628 us; speedup vs baseline: 2.8557x; 1.1192x over previous
//
#include <hip/hip_runtime.h>
#include <cstdint>
#include <cstddef>

static inline int cdiv(int a, int b) { return (a + b - 1) / b; }

__device__ inline float dinvf(float v) {
  return (v > 0.f) ? 1.0f / sqrtf(fmaxf(v, 1e-12f)) : 0.f;
}

__device__ inline float leaky(float t) { return (t > 0.f) ? t : 0.2f * t; }

// ---------------- setup kernels ----------------

__global__ void zero_kernel(float* __restrict__ p, int n) {
  int i = blockIdx.x * 256 + threadIdx.x;
  if (i < n) p[i] = 0.f;
}

// merged: layer-1 front GEMM (blocks [0,Ggemm)) + diag/row-count (blocks >= Ggemm)
__global__ void gemm_count_kernel(const float* __restrict__ x, const float* __restrict__ Wd,
                                  const float* __restrict__ Wp, const float* __restrict__ as,
                                  const float* __restrict__ ad, float* __restrict__ h,
                                  float* __restrict__ xwp, float* __restrict__ ssrc,
                                  float* __restrict__ sdst, int E, int di, int do_, int Ggemm,
                                  const int* __restrict__ idx_u, const float* __restrict__ val_u,
                                  const int* __restrict__ idx_d, const float* __restrict__ val_d,
                                  float* __restrict__ diag, int* __restrict__ cnt_u,
                                  int* __restrict__ cnt_d, int nnz) {
  __shared__ float Wds[64 * 32];
  __shared__ float Wps[64 * 32];
  __shared__ float avec[64];
  if (blockIdx.x >= Ggemm) {
    int i = (blockIdx.x - Ggemm) * 256 + threadIdx.x;
    if (i < nnz) {
      int r = idx_u[i], c = idx_u[nnz + i];
      atomicAdd(&cnt_u[r], 1);
      if (r == c) atomicAdd(&diag[r], val_u[i]);
    } else if (i < 2 * nnz) {
      int j = i - nnz;
      int r = idx_d[j], c = idx_d[nnz + j];
      atomicAdd(&cnt_d[r], 1);
      if (r == c) atomicAdd(&diag[r], val_d[j]);
    }
    return;
  }
  int t = threadIdx.x;
  for (int k = t; k < di * do_; k += 256) {
    Wds[k] = Wd[k];
    Wps[k] = Wp[k];
  }
  if (t < do_) {
    avec[t] = as[t];
    avec[32 + t] = ad[t];
  }
  __syncthreads();
  int f = t & 31, rl = t >> 5;
  int row = blockIdx.x * 8 + rl;
  if (row >= E) return;
  float ah = 0.f, ap = 0.f;
  const float* xr = x + (size_t)row * di;
  if (f < do_) {
    for (int k = 0; k < di; k++) {
      float xv = xr[k];
      ah += xv * Wds[k * do_ + f];
      ap += xv * Wps[k * do_ + f];
    }
  }
  float v1 = (f < do_) ? ah * avec[f] : 0.f;
  float v2 = (f < do_) ? ah * avec[32 + f] : 0.f;
#pragma unroll
  for (int off = 16; off; off >>= 1) {
    v1 += __shfl_xor(v1, off);
    v2 += __shfl_xor(v2, off);
  }
  if (f == 0) {
    ssrc[row] = v1;
    sdst[row] = v2;
  }
  if (f < do_) {
    h[(size_t)row * do_ + f] = ah;
    xwp[(size_t)row * do_ + f] = ap;
  }
}

// two blocks of 1024 threads; block 0 scans cnt_u -> rowptr_u, block 1 cnt_d -> rowptr_d
__global__ void scan2_kernel(const int* __restrict__ cnt_u, int* __restrict__ rowptr_u,
                             const int* __restrict__ cnt_d, int* __restrict__ rowptr_d, int n) {
  const int* cnt = (blockIdx.x == 0) ? cnt_u : cnt_d;
  int* rowptr = (blockIdx.x == 0) ? rowptr_u : rowptr_d;
  __shared__ int part[1024];
  int t = threadIdx.x;
  int base = t * 8;
  int loc[8];
  int s = 0;
#pragma unroll
  for (int k = 0; k < 8; k++) {
    int idx = base + k;
    loc[k] = s;
    s += (idx < n) ? cnt[idx] : 0;
  }
  part[t] = s;
  __syncthreads();
  for (int off = 1; off < 1024; off <<= 1) {
    int v = (t >= off) ? part[t - off] : 0;
    __syncthreads();
    part[t] += v;
    __syncthreads();
  }
  int pre = (t > 0) ? part[t - 1] : 0;
#pragma unroll
  for (int k = 0; k < 8; k++) {
    int idx = base + k;
    if (idx < n) rowptr[idx] = pre + loc[k];
  }
  if (t == 1023) rowptr[n] = part[1023];
}

// fused CSR fill for both matrices; cnt reused as cursor via atomicSub
__global__ void fill2_kernel(const int* __restrict__ idx_u, const float* __restrict__ val_u,
                             const int* __restrict__ idx_d, const float* __restrict__ val_d,
                             const float* __restrict__ diag, const int* __restrict__ rpu,
                             const int* __restrict__ rpd, int* __restrict__ cnt_u,
                             int* __restrict__ cnt_d, int* __restrict__ col_u,
                             float* __restrict__ valn_u, int* __restrict__ col_d,
                             float* __restrict__ valn_d, int nnz) {
  int i = blockIdx.x * 256 + threadIdx.x;
  if (i < nnz) {
    int r = idx_u[i], c = idx_u[nnz + i];
    int p = rpu[r] + atomicSub(&cnt_u[r], 1) - 1;
    col_u[p] = c;
    valn_u[p] = val_u[i] * dinvf(diag[r]) * dinvf(diag[c]);
  } else if (i < 2 * nnz) {
    int j = i - nnz;
    int r = idx_d[j], c = idx_d[nnz + j];
    int p = rpd[r] + atomicSub(&cnt_d[r], 1) - 1;
    col_d[p] = c;
    valn_d[p] = val_d[j] * dinvf(diag[r]) * dinvf(diag[c]);
  }
}

// ---------------- layer kernels ----------------
// Register-cached edge entries: lane L holds entry (beg+L)'s col/val/score.
// Rows with >64 entries use rare fallback loops.

// fused: msg-pass of current layer (width 32) + ReLU + GEMM into next layer (do_next<=32)
// + next-layer attention scalars. wave per row; 4 waves/block.
__global__ void msgemm_kernel(const int* __restrict__ rpu, const int* __restrict__ colu,
                              const float* __restrict__ valu, const int* __restrict__ rpd,
                              const int* __restrict__ cold, const float* __restrict__ vald,
                              const float* __restrict__ h, const float* __restrict__ xwp,
                              const float* __restrict__ ssrc, const float* __restrict__ sdst,
                              const float* __restrict__ Wdn, const float* __restrict__ Wpn,
                              const float* __restrict__ asn, const float* __restrict__ adn,
                              float* __restrict__ h_out, float* __restrict__ xwp_out,
                              float* __restrict__ ssrc_out, float* __restrict__ sdst_out,
                              int do_next, int E) {
  __shared__ float Ws[2048];  // [0..1023] Wd (stride 32), [1024..2047] Wp
  __shared__ float avec[64];
  int t = threadIdx.x;
  for (int idx = t; idx < 32 * do_next; idx += 256) {
    int k = idx / do_next, f = idx % do_next;
    Ws[k * 32 + f] = Wdn[idx];
    Ws[1024 + k * 32 + f] = Wpn[idx];
  }
  if (t < do_next) {
    avec[t] = asn[t];
    avec[32 + t] = adn[t];
  }
  __syncthreads();
  int wid = blockIdx.x * 4 + (t >> 6);
  int lane = t & 63;
  if (wid >= E) return;

  int bu = rpu[wid], eu = rpu[wid + 1];
  int bd = rpd[wid], ed = rpd[wid + 1];
  int lu = eu - bu, ld = ed - bd;
  float ssr = ssrc[wid];

  // load entries into registers (one per lane)
  int cu = 0, cd = 0;
  float vu = 0.f, vd = 0.f, eru = -3.0e38f, erd = -3.0e38f;
  if (lane < lu) {
    cu = colu[bu + lane];
    vu = valu[bu + lane];
    eru = leaky(ssr + sdst[cu]);
  }
  if (lane < ld) {
    cd = cold[bd + lane];
    vd = vald[bd + lane];
    erd = leaky(ssr + sdst[cd]);
  }
  float mu = eru, md = erd;
  for (int j = bu + 64 + lane; j < eu; j += 64) mu = fmaxf(mu, leaky(ssr + sdst[colu[j]]));
  for (int j = bd + 64 + lane; j < ed; j += 64) md = fmaxf(md, leaky(ssr + sdst[cold[j]]));
#pragma unroll
  for (int off = 32; off; off >>= 1) {
    mu = fmaxf(mu, __shfl_xor(mu, off));
    md = fmaxf(md, __shfl_xor(md, off));
  }
  float su = (lane < lu) ? __expf(eru - mu) : 0.f;
  float sd_ = (lane < ld) ? __expf(erd - md) : 0.f;
  for (int j = bu + 64 + lane; j < eu; j += 64) su += __expf(leaky(ssr + sdst[colu[j]]) - mu);
  for (int j = bd + 64 + lane; j < ed; j += 64) sd_ += __expf(leaky(ssr + sdst[cold[j]]) - md);
#pragma unroll
  for (int off = 32; off; off >>= 1) {
    su += __shfl_xor(su, off);
    sd_ += __shfl_xor(sd_, off);
  }
  float invu = 1.0f / (su + 1e-16f);
  float invd = 1.0f / (sd_ + 1e-16f);

  // gather phase: 2 entries x 32 features; entry state via shfl from registers
  int f = lane & 31, eo = lane >> 5;
  float a = 0.f;
  int limu = lu < 64 ? lu : 64;
  for (int j = eo; j < limu; j += 2) {
    float e = __shfl(eru, j);
    int c = __shfl(cu, j);
    float v = __shfl(vu, j);
    float al = __expf(e - mu) * invu;
    a += al * h[(size_t)c * 32 + f] + v * xwp[(size_t)c * 32 + f];
  }
  for (int j = bu + 64 + eo; j < eu; j += 2) {  // rare overflow
    int c = colu[j];
    float v = valu[j];
    float al = __expf(leaky(ssr + sdst[c]) - mu) * invu;
    a += al * h[(size_t)c * 32 + f] + v * xwp[(size_t)c * 32 + f];
  }
  int limd = ld < 64 ? ld : 64;
  for (int j = eo; j < limd; j += 2) {
    float e = __shfl(erd, j);
    int c = __shfl(cd, j);
    float v = __shfl(vd, j);
    float al = __expf(e - md) * invd;
    a += al * h[(size_t)c * 32 + f] + v * xwp[(size_t)c * 32 + f];
  }
  for (int j = bd + 64 + eo; j < ed; j += 2) {  // rare overflow
    int c = cold[j];
    float v = vald[j];
    float al = __expf(leaky(ssr + sdst[c]) - md) * invd;
    a += al * h[(size_t)c * 32 + f] + v * xwp[(size_t)c * 32 + f];
  }
  a += __shfl_xor(a, 32);  // all 64 lanes hold feature f
  float x = fmaxf(a, 0.f);

  // GEMM into next layer: lanes<32 compute h' (Wd), lanes>=32 compute xwp' (Wp)
  const float* W = (lane < 32) ? Ws : (Ws + 1024);
  float acc1 = 0.f;
#pragma unroll
  for (int k = 0; k < 32; k++) {
    float xk = __shfl(x, k);
    acc1 += xk * W[k * 32 + f];
  }
  if (f < do_next) {
    if (lane < 32) h_out[(size_t)wid * do_next + f] = acc1;
    else xwp_out[(size_t)wid * do_next + f] = acc1;
  }
  float v1 = (lane < 32 && f < do_next) ? acc1 * avec[f] : 0.f;
  float v2 = (lane < 32 && f < do_next) ? acc1 * avec[32 + f] : 0.f;
#pragma unroll
  for (int off = 32; off; off >>= 1) {
    v1 += __shfl_xor(v1, off);
    v2 += __shfl_xor(v2, off);
  }
  if (lane == 0) {
    ssrc_out[wid] = v1;
    sdst_out[wid] = v2;
  }
}

// final-layer message pass (feature width do_ <= 32), writes ReLU'd rows
__global__ void msg_kernel(const int* __restrict__ rpu, const int* __restrict__ colu,
                           const float* __restrict__ valu, const int* __restrict__ rpd,
                           const int* __restrict__ cold, const float* __restrict__ vald,
                           const float* __restrict__ h, const float* __restrict__ xwp,
                           const float* __restrict__ ssrc, const float* __restrict__ sdst,
                           float* __restrict__ out, int do_, int E) {
  int wid = (blockIdx.x * blockDim.x + threadIdx.x) >> 6;
  int lane = threadIdx.x & 63;
  if (wid >= E) return;
  int bu = rpu[wid], eu = rpu[wid + 1];
  int bd = rpd[wid], ed = rpd[wid + 1];
  int lu = eu - bu, ld = ed - bd;
  float ssr = ssrc[wid];

  int cu = 0, cd = 0;
  float vu = 0.f, vd = 0.f, eru = -3.0e38f, erd = -3.0e38f;
  if (lane < lu) {
    cu = colu[bu + lane];
    vu = valu[bu + lane];
    eru = leaky(ssr + sdst[cu]);
  }
  if (lane < ld) {
    cd = cold[bd + lane];
    vd = vald[bd + lane];
    erd = leaky(ssr + sdst[cd]);
  }
  float mu = eru, md = erd;
  for (int j = bu + 64 + lane; j < eu; j += 64) mu = fmaxf(mu, leaky(ssr + sdst[colu[j]]));
  for (int j = bd + 64 + lane; j < ed; j += 64) md = fmaxf(md, leaky(ssr + sdst[cold[j]]));
#pragma unroll
  for (int off = 32; off; off >>= 1) {
    mu = fmaxf(mu, __shfl_xor(mu, off));
    md = fmaxf(md, __shfl_xor(md, off));
  }
  float su = (lane < lu) ? __expf(eru - mu) : 0.f;
  float sd_ = (lane < ld) ? __expf(erd - md) : 0.f;
  for (int j = bu + 64 + lane; j < eu; j += 64) su += __expf(leaky(ssr + sdst[colu[j]]) - mu);
  for (int j = bd + 64 + lane; j < ed; j += 64) sd_ += __expf(leaky(ssr + sdst[cold[j]]) - md);
#pragma unroll
  for (int off = 32; off; off >>= 1) {
    su += __shfl_xor(su, off);
    sd_ += __shfl_xor(sd_, off);
  }
  float invu = 1.0f / (su + 1e-16f);
  float invd = 1.0f / (sd_ + 1e-16f);

  int f = lane & 31, eo = lane >> 5;
  float a = 0.f;
  int limu = lu < 64 ? lu : 64;
  for (int j = eo; j < limu; j += 2) {
    float e = __shfl(eru, j);
    int c = __shfl(cu, j);
    float v = __shfl(vu, j);
    float al = __expf(e - mu) * invu;
    if (f < do_) a += al * h[(size_t)c * do_ + f] + v * xwp[(size_t)c * do_ + f];
  }
  for (int j = bu + 64 + eo; j < eu; j += 2) {
    int c = colu[j];
    float v = valu[j];
    float al = __expf(leaky(ssr + sdst[c]) - mu) * invu;
    if (f < do_) a += al * h[(size_t)c * do_ + f] + v * xwp[(size_t)c * do_ + f];
  }
  int limd = ld < 64 ? ld : 64;
  for (int j = eo; j < limd; j += 2) {
    float e = __shfl(erd, j);
    int c = __shfl(cd, j);
    float v = __shfl(vd, j);
    float al = __expf(e - md) * invd;
    if (f < do_) a += al * h[(size_t)c * do_ + f] + v * xwp[(size_t)c * do_ + f];
  }
  for (int j = bd + 64 + eo; j < ed; j += 2) {
    int c = cold[j];
    float v = vald[j];
    float al = __expf(leaky(ssr + sdst[c]) - md) * invd;
    if (f < do_) a += al * h[(size_t)c * do_ + f] + v * xwp[(size_t)c * do_ + f];
  }
  a += __shfl_xor(a, 32);
  if (lane < do_) out[(size_t)wid * do_ + lane] = fmaxf(a, 0.f);
}

// ---------------- pooling + softmax (atomic-free; batch is sorted) ----------------

__global__ void pool_softmax_kernel(const float* __restrict__ x, const int* __restrict__ batch,
                                    float* __restrict__ out, int E, int do_, int B) {
  int b = blockIdx.x;
  int t = threadIdx.x;
  __shared__ int bounds[2];
  if (t < 2) {
    int target = b + t;
    int lo = 0, hi = E;
    while (lo < hi) {
      int mid = (lo + hi) >> 1;
      if (batch[mid] < target) lo = mid + 1;
      else hi = mid;
    }
    bounds[t] = lo;
  }
  __syncthreads();
  int lo = bounds[0], hi = bounds[1];
  float p[16];
#pragma unroll
  for (int f = 0; f < 16; f++) p[f] = 0.f;
  for (int r = lo + t; r < hi; r += 256) {
#pragma unroll
    for (int f = 0; f < 16; f++)
      if (f < do_) p[f] += x[(size_t)r * do_ + f];
  }
#pragma unroll
  for (int f = 0; f < 16; f++) {
    if (f < do_) {
#pragma unroll
      for (int off = 32; off; off >>= 1) p[f] += __shfl_xor(p[f], off);
    }
  }
  __shared__ float sm[4][16];
  int wv = t >> 6, ln = t & 63;
  if (ln == 0) {
#pragma unroll
    for (int f = 0; f < 16; f++)
      if (f < do_) sm[wv][f] = p[f];
  }
  __syncthreads();
  if (t == 0) {
    float cnt = fmaxf((float)(hi - lo), 1.f);
    float q[16];
    float mx = -1e30f;
    for (int f = 0; f < do_; f++) {
      q[f] = (sm[0][f] + sm[1][f] + sm[2][f] + sm[3][f]) / cnt;
      mx = fmaxf(mx, q[f]);
    }
    float s = 0.f;
    for (int f = 0; f < do_; f++) {
      q[f] = __expf(q[f] - mx);
      s += q[f];
    }
    for (int f = 0; f < do_; f++) out[b * do_ + f] = q[f] / s;
  }
}

// ---------------- launch ----------------

extern "C" void kernel_launch(void* const* d_in, const int* in_sizes, int n_in,
                              void* d_out, int out_size, void* d_ws, size_t ws_size,
                              hipStream_t stream) {
  const float* X1 = (const float*)d_in[0];
  const int* idx_u = (const int*)d_in[1];
  const float* val_u = (const float*)d_in[2];
  const int* idx_d = (const int*)d_in[3];
  const float* val_d = (const float*)d_in[4];
  const int* batch1 = (const int*)d_in[5];

  const int E = in_sizes[5];
  const int NNZ = in_sizes[2];
  const int F_IN = in_sizes[0] / E;
  const int OUT = in_sizes[19];
  const int Bn = out_size / OUT;

  // bump allocator over workspace
  char* ws = (char*)d_ws;
  size_t off = 0;
  auto alloc = [&](size_t bytes) -> char* {
    char* p = ws + off;
    off = (off + bytes + 255) & ~(size_t)255;
    return p;
  };

  // zero region (contiguous at start of ws)
  float* d_diag = (float*)alloc((size_t)E * 4);
  int* cnt_u = (int*)alloc((size_t)E * 4);
  int* cnt_d = (int*)alloc((size_t)E * 4);
  size_t zero_end = off;

  int* rowptr_u = (int*)alloc((size_t)(E + 1) * 4);
  int* rowptr_d = (int*)alloc((size_t)(E + 1) * 4);
  int* col_u = (int*)alloc((size_t)NNZ * 4);
  float* valn_u = (float*)alloc((size_t)NNZ * 4);
  int* col_d = (int*)alloc((size_t)NNZ * 4);
  float* valn_d = (float*)alloc((size_t)NNZ * 4);
  float* hA = (float*)alloc((size_t)E * 32 * 4);
  float* xwpA = (float*)alloc((size_t)E * 32 * 4);
  float* hB = (float*)alloc((size_t)E * 32 * 4);
  float* xwpB = (float*)alloc((size_t)E * 32 * 4);
  float* acc = (float*)alloc((size_t)E * 32 * 4);
  float* ssA = (float*)alloc((size_t)E * 4);
  float* sdA = (float*)alloc((size_t)E * 4);
  float* ssB = (float*)alloc((size_t)E * 4);
  float* sdB = (float*)alloc((size_t)E * 4);
  (void)ws_size;

  const float* W1d = (const float*)d_in[6];
  const float* a1s = (const float*)d_in[7];
  const float* a1d = (const float*)d_in[8];
  const float* W1p = (const float*)d_in[9];
  const int H = in_sizes[7];  // 32

  int zn = (int)(zero_end / 4);
  zero_kernel<<<cdiv(zn, 256), 256, 0, stream>>>((float*)d_ws, zn);

  int Ggemm = cdiv(E, 8);
  int Gcnt = cdiv(2 * NNZ, 256);
  gemm_count_kernel<<<Ggemm + Gcnt, 256, 0, stream>>>(
      X1, W1d, W1p, a1s, a1d, hA, xwpA, ssA, sdA, E, F_IN, H, Ggemm,
      idx_u, val_u, idx_d, val_d, d_diag, cnt_u, cnt_d, NNZ);
  scan2_kernel<<<2, 1024, 0, stream>>>(cnt_u, rowptr_u, cnt_d, rowptr_d, E);
  fill2_kernel<<<cdiv(2 * NNZ, 256), 256, 0, stream>>>(idx_u, val_u, idx_d, val_d, d_diag,
                                                       rowptr_u, rowptr_d, cnt_u, cnt_d,
                                                       col_u, valn_u, col_d, valn_d, NNZ);

  // layers 1-3 msg fused with layers 2-4 GEMM front
  float* hin = hA; float* xin = xwpA; float* ssin = ssA; float* sdin = sdA;
  float* hout = hB; float* xout = xwpB; float* ssout = ssB; float* sdout = sdB;
  for (int li = 0; li < 3; li++) {
    const float* Wdn = (const float*)d_in[6 + 4 * (li + 1) + 0];
    const float* asn = (const float*)d_in[6 + 4 * (li + 1) + 1];
    const float* adn = (const float*)d_in[6 + 4 * (li + 1) + 2];
    const float* Wpn = (const float*)d_in[6 + 4 * (li + 1) + 3];
    int do_next = in_sizes[6 + 4 * (li + 1) + 1];
    msgemm_kernel<<<cdiv(E, 4), 256, 0, stream>>>(rowptr_u, col_u, valn_u, rowptr_d, col_d,
                                                  valn_d, hin, xin, ssin, sdin, Wdn, Wpn,
                                                  asn, adn, hout, xout, ssout, sdout,
                                                  do_next, E);
    float* tp;
    tp = hin; hin = hout; hout = tp;
    tp = xin; xin = xout; xout = tp;
    tp = ssin; ssin = ssout; ssout = tp;
    tp = sdin; sdin = sdout; sdout = tp;
  }

  // layer 4 msg (do=OUT)
  msg_kernel<<<cdiv(E, 4), 256, 0, stream>>>(rowptr_u, col_u, valn_u, rowptr_d, col_d,
                                             valn_d, hin, xin, ssin, sdin, acc, OUT, E);

  pool_softmax_kernel<<<Bn, 256, 0, stream>>>(acc, batch1, (float*)d_out, E, OUT, Bn);
}